// Round 1
// baseline (1522.966 us; speedup 1.0000x reference)
//
#include <hip/hip_runtime.h>
#include <hip/hip_bf16.h>

typedef __bf16 bf16_t;
typedef __bf16 bf16x8 __attribute__((ext_vector_type(8)));
typedef float f32x4 __attribute__((ext_vector_type(4)));

#define HIDDEN 3584
#define NQH 16
#define NKVH 8
#define DH 256
#define SEQ 4096
#define QKV_COLS 8192   // (NQH + 2*NKVH) * DH
#define Q_SIZE 4096     // NQH * DH
#define KV_SIZE 2048    // NKVH * DH
#define WINDOW 2048
#define SCALE_F 0.0625f // 256^-0.5
#define CAP_F 50.0f

__device__ __forceinline__ float fast_tanh(float x) {
  // 1 - 2/(e^{2x}+1); saturates correctly at +-1 for |x| large
  return 1.0f - 2.0f / (__expf(2.0f * x) + 1.0f);
}

// ---------------- f32 -> bf16 conversion (vectorized) ----------------
__global__ __launch_bounds__(256) void cvt_f32_to_bf16(const float* __restrict__ src,
                                                       bf16_t* __restrict__ dst, long n8) {
  long i = (long)blockIdx.x * 256 + threadIdx.x;
  if (i >= n8) return;
  const float4* s4 = (const float4*)src;
  float4 a = s4[i * 2];
  float4 b = s4[i * 2 + 1];
  bf16x8 o;
  o[0] = (bf16_t)a.x; o[1] = (bf16_t)a.y; o[2] = (bf16_t)a.z; o[3] = (bf16_t)a.w;
  o[4] = (bf16_t)b.x; o[5] = (bf16_t)b.y; o[6] = (bf16_t)b.z; o[7] = (bf16_t)b.w;
  *(bf16x8*)(dst + i * 8) = o;
}

// ---------------- bf16 GEMM, C[M,N] = A[M,K] * B[N,K]^T ----------------
// 128x128 block tile, 4 waves (2x2), each wave 64x64 = 4x4 frags of 16x16x32 MFMA.
template <bool OUT_BF16>
__global__ __launch_bounds__(256) void gemm_bt(const bf16_t* __restrict__ A,
                                               const bf16_t* __restrict__ B,
                                               void* __restrict__ Cout,
                                               int M, int N, int K) {
  __shared__ bf16_t As[128][40];  // +8 pad: 80B row stride -> ~2-way on b128 reads
  __shared__ bf16_t Bs[128][40];
  int t = threadIdx.x;
  int lane = t & 63, w = t >> 6;
  int wr = w >> 1, wc = w & 1;
  int r16 = lane & 15, g = lane >> 4;
  long bm = (long)blockIdx.y * 128, bn = (long)blockIdx.x * 128;
  f32x4 acc[4][4] = {};
  for (int k0 = 0; k0 < K; k0 += 32) {
#pragma unroll
    for (int c = 0; c < 2; ++c) {
      int f = t * 8 + c * 2048;
      int row = f >> 5, col = f & 31;
      *(bf16x8*)&As[row][col] = *(const bf16x8*)&A[(bm + row) * K + k0 + col];
      *(bf16x8*)&Bs[row][col] = *(const bf16x8*)&B[(bn + row) * K + k0 + col];
    }
    __syncthreads();
    bf16x8 af[4], bfr[4];
#pragma unroll
    for (int i = 0; i < 4; ++i) af[i] = *(const bf16x8*)&As[wr * 64 + i * 16 + r16][g * 8];
#pragma unroll
    for (int j = 0; j < 4; ++j) bfr[j] = *(const bf16x8*)&Bs[wc * 64 + j * 16 + r16][g * 8];
#pragma unroll
    for (int i = 0; i < 4; ++i)
#pragma unroll
      for (int j = 0; j < 4; ++j)
        acc[i][j] = __builtin_amdgcn_mfma_f32_16x16x32_bf16(af[i], bfr[j], acc[i][j], 0, 0, 0);
    __syncthreads();
  }
#pragma unroll
  for (int i = 0; i < 4; ++i)
#pragma unroll
    for (int j = 0; j < 4; ++j)
#pragma unroll
      for (int r = 0; r < 4; ++r) {
        long row = bm + wr * 64 + i * 16 + g * 4 + r;
        long col = bn + wc * 64 + j * 16 + r16;
        if (OUT_BF16) ((bf16_t*)Cout)[row * N + col] = (bf16_t)acc[i][j][r];
        else          ((float*)Cout)[row * N + col]  = acc[i][j][r];
      }
}

// ---------------- RoPE (neox), in-place on q,k of qkv ----------------
__global__ __launch_bounds__(256) void rope_kernel(bf16_t* __restrict__ qkv) {
  long idx = (long)blockIdx.x * 256 + threadIdx.x;  // SEQ * 24 * 128 threads
  int i = (int)(idx & 127);
  long rem = idx >> 7;
  int head = (int)(rem % 24);
  int s = (int)(rem / 24);
  int base = head < NQH ? head * DH : Q_SIZE + (head - NQH) * DH;
  long p1 = (long)s * QKV_COLS + base + i;
  long p2 = p1 + 128;
  float x1 = (float)qkv[p1], x2 = (float)qkv[p2];
  // inv_freq = 10000^(-i/128) = 2^(-i * log2(10000)/128)
  float inv_freq = exp2f((float)i * -0.10381025296522976f);
  float fr = (float)s * inv_freq;
  float sn, cs;
  sincosf(fr, &sn, &cs);  // precise range reduction (pos up to 4095 rad)
  qkv[p1] = (bf16_t)(x1 * cs - x2 * sn);
  qkv[p2] = (bf16_t)(x2 * cs + x1 * sn);
}

// ---------------- V transpose: vt[kv_col][s] = qkv[s][6144 + kv_col] ----------------
__global__ __launch_bounds__(256) void vtrans_kernel(const bf16_t* __restrict__ qkv,
                                                     bf16_t* __restrict__ vt) {
  __shared__ bf16_t tile[64][72];
  int t = threadIdx.x;
  long s0 = (long)blockIdx.x * 64;
  long c0 = (long)blockIdx.y * 64;
#pragma unroll
  for (int it = 0; it < 2; ++it) {
    int u = t + it * 256;
    int sr = u >> 3, ch = u & 7;
    bf16x8 v = *(const bf16x8*)&qkv[(s0 + sr) * QKV_COLS + (Q_SIZE + KV_SIZE) + c0 + ch * 8];
    *(bf16x8*)&tile[sr][ch * 8] = v;
  }
  __syncthreads();
#pragma unroll
  for (int it = 0; it < 2; ++it) {
    int u = t + it * 256;
    int cr = u >> 3, ch = u & 7;
    bf16x8 o;
#pragma unroll
    for (int j = 0; j < 8; ++j) o[j] = tile[ch * 8 + j][cr];
    *(bf16x8*)&vt[(c0 + cr) * SEQ + s0 + ch * 8] = o;
  }
}

// ---------------- flash attention with softcap + sliding window + GQA ----------------
// grid (SEQ/64, NQH); 4 waves/block, each wave owns 16 q-rows; 32-key tiles.
__global__ __launch_bounds__(256) void attn_kernel(const bf16_t* __restrict__ qkv,
                                                   const bf16_t* __restrict__ vt,
                                                   bf16_t* __restrict__ attn_out) {
  __shared__ bf16_t Pl[4][16][40];
  int t = threadIdx.x;
  int lane = t & 63, w = t >> 6;
  int r16 = lane & 15, g = lane >> 4;
  int h = blockIdx.y;
  int qb = blockIdx.x;
  int kvh = h >> 1;               // GQA: q head h uses kv head h/2
  int qw = qb * 64 + w * 16;      // wave's first q row
  bf16x8 qf[8];
  long qoff = (long)(qw + r16) * QKV_COLS + h * DH + g * 8;
#pragma unroll
  for (int kk = 0; kk < 8; ++kk) qf[kk] = *(const bf16x8*)&qkv[qoff + kk * 32];
  f32x4 acc[16] = {};
  float m_run[4], l_run[4];
#pragma unroll
  for (int r = 0; r < 4; ++r) { m_run[r] = -1e30f; l_run[r] = 0.0f; }
  int lo = qb * 64 - (WINDOW - 1); if (lo < 0) lo = 0;
  int t0 = lo >> 5;
  int t1 = (qb * 64 + 64) >> 5;
  const bf16_t* kbaseptr = qkv + Q_SIZE + (long)kvh * DH;
  const bf16_t* vbaseptr = vt + (long)kvh * DH * SEQ;
  for (int tt = t0; tt < t1; ++tt) {
    int kb = tt * 32;
    f32x4 sc0 = {0.f, 0.f, 0.f, 0.f}, sc1 = {0.f, 0.f, 0.f, 0.f};
#pragma unroll
    for (int kk = 0; kk < 8; ++kk) {
      bf16x8 kf0 = *(const bf16x8*)&kbaseptr[(long)(kb + r16) * QKV_COLS + kk * 32 + g * 8];
      sc0 = __builtin_amdgcn_mfma_f32_16x16x32_bf16(qf[kk], kf0, sc0, 0, 0, 0);
      bf16x8 kf1 = *(const bf16x8*)&kbaseptr[(long)(kb + 16 + r16) * QKV_COLS + kk * 32 + g * 8];
      sc1 = __builtin_amdgcn_mfma_f32_16x16x32_bf16(qf[kk], kf1, sc1, 0, 0, 0);
    }
    float scale_o[4];
#pragma unroll
    for (int r = 0; r < 4; ++r) {
      int q = qw + g * 4 + r;
      int k0i = kb + r16, k1i = kb + 16 + r16;
      float v0 = CAP_F * fast_tanh(sc0[r] * (SCALE_F / CAP_F));
      float v1 = CAP_F * fast_tanh(sc1[r] * (SCALE_F / CAP_F));
      if (!((k0i <= q) && (q - k0i < WINDOW))) v0 = -1e30f;
      if (!((k1i <= q) && (q - k1i < WINDOW))) v1 = -1e30f;
      float tm = fmaxf(v0, v1);
      tm = fmaxf(tm, __shfl_xor(tm, 1));
      tm = fmaxf(tm, __shfl_xor(tm, 2));
      tm = fmaxf(tm, __shfl_xor(tm, 4));
      tm = fmaxf(tm, __shfl_xor(tm, 8));
      float nm = fmaxf(m_run[r], tm);
      float p0 = __expf(v0 - nm);
      float p1 = __expf(v1 - nm);
      float rs = p0 + p1;
      rs += __shfl_xor(rs, 1);
      rs += __shfl_xor(rs, 2);
      rs += __shfl_xor(rs, 4);
      rs += __shfl_xor(rs, 8);
      float so = __expf(m_run[r] - nm);  // fully-masked prefix tiles are wiped by so=0 later
      l_run[r] = l_run[r] * so + rs;
      m_run[r] = nm;
      scale_o[r] = so;
      Pl[w][g * 4 + r][r16]      = (bf16_t)p0;
      Pl[w][g * 4 + r][16 + r16] = (bf16_t)p1;
    }
#pragma unroll
    for (int dt = 0; dt < 16; ++dt)
#pragma unroll
      for (int r = 0; r < 4; ++r) acc[dt][r] *= scale_o[r];
    __syncthreads();
    bf16x8 pa = *(const bf16x8*)&Pl[w][r16][g * 8];
#pragma unroll
    for (int dt = 0; dt < 16; ++dt) {
      bf16x8 vf = *(const bf16x8*)&vbaseptr[(long)(dt * 16 + r16) * SEQ + kb + g * 8];
      acc[dt] = __builtin_amdgcn_mfma_f32_16x16x32_bf16(pa, vf, acc[dt], 0, 0, 0);
    }
    __syncthreads();
  }
#pragma unroll
  for (int dt = 0; dt < 16; ++dt)
#pragma unroll
    for (int r = 0; r < 4; ++r) {
      long row = qw + g * 4 + r;
      attn_out[row * Q_SIZE + h * DH + dt * 16 + r16] = (bf16_t)(acc[dt][r] / l_run[r]);
    }
}

extern "C" void kernel_launch(void* const* d_in, const int* in_sizes, int n_in,
                              void* d_out, int out_size, void* d_ws, size_t ws_size,
                              hipStream_t stream) {
  const float* hid_f  = (const float*)d_in[1];
  const float* wqkv_f = (const float*)d_in[2];
  const float* wo_f   = (const float*)d_in[3];
  float* out = (float*)d_out;
  char* ws = (char*)d_ws;
  // workspace layout (bytes); attn aliases hid region (dead after GEMM1),
  // vt aliases the tail of wqkv region (dead after GEMM1).
  bf16_t* qkv    = (bf16_t*)(ws);                 // 67,108,864
  bf16_t* wo_b   = (bf16_t*)(ws + 67108864);      // 29,360,128
  bf16_t* hid_b  = (bf16_t*)(ws + 96468992);      // 29,360,128
  bf16_t* wqkv_b = (bf16_t*)(ws + 125829120);     // 58,720,256 (total 184,549,376)
  bf16_t* attn_b = (bf16_t*)(ws + 96468992);      // 33,554,432 alias
  bf16_t* vt     = (bf16_t*)(ws + 130023424);     // 16,777,216 alias

  cvt_f32_to_bf16<<<7168, 256, 0, stream>>>(hid_f, hid_b, 14680064 / 8);
  cvt_f32_to_bf16<<<14336, 256, 0, stream>>>(wqkv_f, wqkv_b, 29360128 / 8);
  cvt_f32_to_bf16<<<7168, 256, 0, stream>>>(wo_f, wo_b, 14680064 / 8);
  gemm_bt<true><<<dim3(64, 32), 256, 0, stream>>>(hid_b, wqkv_b, qkv, SEQ, QKV_COLS, HIDDEN);
  rope_kernel<<<49152, 256, 0, stream>>>(qkv);
  vtrans_kernel<<<dim3(64, 32), 256, 0, stream>>>(qkv, vt);
  attn_kernel<<<dim3(64, 16), 256, 0, stream>>>(qkv, vt, attn_b);
  gemm_bt<false><<<dim3(28, 32), 256, 0, stream>>>(attn_b, wo_b, out, SEQ, HIDDEN, Q_SIZE);
}

// Round 3
// 1108.144 us; speedup vs baseline: 1.3743x; 1.3743x over previous
//
#include <hip/hip_runtime.h>
#include <hip/hip_bf16.h>

typedef __bf16 bf16_t;
typedef __bf16 bf16x8 __attribute__((ext_vector_type(8)));
typedef float f32x4 __attribute__((ext_vector_type(4)));

#define HIDDEN 3584
#define NQH 16
#define NKVH 8
#define DH 256
#define SEQ 4096
#define QKV_COLS 8192   // (NQH + 2*NKVH) * DH
#define Q_SIZE 4096     // NQH * DH
#define KV_SIZE 2048    // NKVH * DH
#define WINDOW 2048
#define SCALE_F 0.0625f // 256^-0.5
#define CAP_F 50.0f
#define SM_MAX 12.0f    // fixed softmax max; scores capped to +-50 by tanh -> always safe

__device__ __forceinline__ float fast_tanh(float x) {
  return 1.0f - 2.0f / (__expf(2.0f * x) + 1.0f);
}

__device__ __forceinline__ void gload16(const bf16_t* g, bf16_t* l) {
  __builtin_amdgcn_global_load_lds((__attribute__((address_space(1))) void*)g,
                                   (__attribute__((address_space(3))) void*)l, 16, 0, 0);
}

// ---------------- f32 -> bf16 conversion (vectorized) ----------------
__global__ __launch_bounds__(256) void cvt_f32_to_bf16(const float* __restrict__ src,
                                                       bf16_t* __restrict__ dst, long n8) {
  long i = (long)blockIdx.x * 256 + threadIdx.x;
  if (i >= n8) return;
  const float4* s4 = (const float4*)src;
  float4 a = s4[i * 2];
  float4 b = s4[i * 2 + 1];
  bf16x8 o;
  o[0] = (bf16_t)a.x; o[1] = (bf16_t)a.y; o[2] = (bf16_t)a.z; o[3] = (bf16_t)a.w;
  o[4] = (bf16_t)b.x; o[5] = (bf16_t)b.y; o[6] = (bf16_t)b.z; o[7] = (bf16_t)b.w;
  *(bf16x8*)(dst + i * 8) = o;
}

// ---------------- bf16 GEMM, C[M,N] = A[M,K] * B[N,K]^T ----------------
// m97 structure: 128x128 tile, BK=32, global_load_lds width-16 staging with
// source pre-swizzle (phys slot s holds logical chunk s^(row&3)).
template <bool OUT_BF16>
__global__ __launch_bounds__(256) void gemm_bt(const bf16_t* __restrict__ A,
                                               const bf16_t* __restrict__ B,
                                               void* __restrict__ Cout,
                                               int M, int N, int K) {
  __shared__ bf16_t As[128 * 32];
  __shared__ bf16_t Bs[128 * 32];
  int t = threadIdx.x;
  int lane = t & 63, w = t >> 6;
  int wr = w >> 1, wc = w & 1;
  int r16 = lane & 15, g = lane >> 4;
  long bm = (long)blockIdx.y * 128, bn = (long)blockIdx.x * 128;
  // staging: seg = w*2+c covers rows seg*16..+16; lane -> row seg*16+(lane>>2), slot lane&3
  int srow = w * 32 + (lane >> 2);
  int ch = (lane & 3) ^ ((lane >> 2) & 3);  // logical chunk loaded into phys slot lane&3
  const bf16_t* gA0 = A + (bm + srow) * K + ch * 8;
  const bf16_t* gA1 = gA0 + 16 * K;
  const bf16_t* gB0 = B + (bn + srow) * K + ch * 8;
  const bf16_t* gB1 = gB0 + 16 * K;
  bf16_t* lA = As + w * 1024;
  bf16_t* lB = Bs + w * 1024;
  int xsl = (g ^ (r16 & 3)) * 8;  // swizzled read column (bytes/2)
  f32x4 acc[4][4] = {};
  for (int k0 = 0; k0 < K; k0 += 32) {
    gload16(gA0, lA); gload16(gA1, lA + 512);
    gload16(gB0, lB); gload16(gB1, lB + 512);
    gA0 += 32; gA1 += 32; gB0 += 32; gB1 += 32;
    __syncthreads();
    bf16x8 af[4], bfr[4];
#pragma unroll
    for (int i = 0; i < 4; ++i) af[i] = *(const bf16x8*)&As[(wr * 64 + i * 16 + r16) * 32 + xsl];
#pragma unroll
    for (int j = 0; j < 4; ++j) bfr[j] = *(const bf16x8*)&Bs[(wc * 64 + j * 16 + r16) * 32 + xsl];
#pragma unroll
    for (int i = 0; i < 4; ++i)
#pragma unroll
      for (int j = 0; j < 4; ++j)
        acc[i][j] = __builtin_amdgcn_mfma_f32_16x16x32_bf16(af[i], bfr[j], acc[i][j], 0, 0, 0);
    __syncthreads();
  }
#pragma unroll
  for (int i = 0; i < 4; ++i)
#pragma unroll
    for (int j = 0; j < 4; ++j)
#pragma unroll
      for (int r = 0; r < 4; ++r) {
        long row = bm + wr * 64 + i * 16 + g * 4 + r;
        long col = bn + wc * 64 + j * 16 + r16;
        if (OUT_BF16) ((bf16_t*)Cout)[row * N + col] = (bf16_t)acc[i][j][r];
        else          ((float*)Cout)[row * N + col]  = acc[i][j][r];
      }
}

// ---------------- RoPE (neox), in-place on q,k of qkv ----------------
__global__ __launch_bounds__(256) void rope_kernel(bf16_t* __restrict__ qkv) {
  long idx = (long)blockIdx.x * 256 + threadIdx.x;
  int i = (int)(idx & 127);
  long rem = idx >> 7;
  int head = (int)(rem % 24);
  int s = (int)(rem / 24);
  int base = head < NQH ? head * DH : Q_SIZE + (head - NQH) * DH;
  long p1 = (long)s * QKV_COLS + base + i;
  long p2 = p1 + 128;
  float x1 = (float)qkv[p1], x2 = (float)qkv[p2];
  float inv_freq = exp2f((float)i * -0.10381025296522976f);
  float fr = (float)s * inv_freq;
  float sn, cs;
  sincosf(fr, &sn, &cs);
  qkv[p1] = (bf16_t)(x1 * cs - x2 * sn);
  qkv[p2] = (bf16_t)(x2 * cs + x1 * sn);
}

// ---------------- V transpose: vt[kv_col][s] = qkv[s][6144 + kv_col] ----------------
__global__ __launch_bounds__(256) void vtrans_kernel(const bf16_t* __restrict__ qkv,
                                                     bf16_t* __restrict__ vt) {
  __shared__ bf16_t tile[64][72];
  int t = threadIdx.x;
  long s0 = (long)blockIdx.x * 64;
  long c0 = (long)blockIdx.y * 64;
#pragma unroll
  for (int it = 0; it < 2; ++it) {
    int u = t + it * 256;
    int sr = u >> 3, ch = u & 7;
    bf16x8 v = *(const bf16x8*)&qkv[(s0 + sr) * QKV_COLS + (Q_SIZE + KV_SIZE) + c0 + ch * 8];
    *(bf16x8*)&tile[sr][ch * 8] = v;
  }
  __syncthreads();
#pragma unroll
  for (int it = 0; it < 2; ++it) {
    int u = t + it * 256;
    int cr = u >> 3, ch = u & 7;
    bf16x8 o;
#pragma unroll
    for (int j = 0; j < 8; ++j) o[j] = tile[ch * 8 + j][cr];
    *(bf16x8*)&vt[(c0 + cr) * SEQ + s0 + ch * 8] = o;
  }
}

// ---------------- flash attention: softcap + sliding window + GQA ----------------
// Block: 128 q rows x 1 head, 4 waves x 32 rows. 64-key tiles.
// K tile [64][256] and V^T tile [256][64] staged via global_load_lds with
// pre-swizzled source (phys 16B slot s holds logical chunk s^(row&7)).
// Fixed-max softmax (scores in [-50,50] by softcap): p = exp(v - 12).
__global__ __launch_bounds__(256, 2) void attn_kernel(const bf16_t* __restrict__ qkv,
                                                      const bf16_t* __restrict__ vt,
                                                      bf16_t* __restrict__ attn_out) {
  __shared__ bf16_t Ks[64 * 256];   // 32 KB
  __shared__ bf16_t Vs[256 * 64];   // 32 KB
  __shared__ bf16_t Pl[4 * 2048];   // 16 KB, 4KB per wave, XOR-swizzled
  int t = threadIdx.x;
  int lane = t & 63, w = t >> 6;
  int r16 = lane & 15, g = lane >> 4;
  // XCD swizzle: blocks with same head land on same XCD's L2
  int bid = blockIdx.x;
  int swz = (bid & 7) * 64 + (bid >> 3);
  int h = swz >> 5;
  int qb = swz & 31;
  int kvh = h >> 1;
  int qw = qb * 128 + w * 32;
  // Q fragments in registers: 32 rows x 256 cols
  bf16x8 qf[2][8];
#pragma unroll
  for (int rf = 0; rf < 2; ++rf) {
    long qoff = (long)(qw + rf * 16 + r16) * QKV_COLS + h * DH + g * 8;
#pragma unroll
    for (int kk = 0; kk < 8; ++kk) qf[rf][kk] = *(const bf16x8*)&qkv[qoff + kk * 32];
  }
  f32x4 acc[2][16] = {};
  float lsum[2][4] = {};
  int lrK = lane >> 5, slK = lane & 31;  // K stage: 2 rows/call, 32 slots/row
  int lrV = lane >> 3, slV = lane & 7;   // V stage: 8 rows/call, 8 slots/row
  const bf16_t* kg = qkv + Q_SIZE + (long)kvh * DH;
  const bf16_t* vg = vt + (long)kvh * DH * SEQ;
  bf16_t* ksl = Ks + w * 4096;
  bf16_t* vsl = Vs + w * 4096;
  bf16_t* pw = Pl + w * 2048;
  int t0 = qb * 128 - (WINDOW - 1);
  t0 = t0 > 0 ? (t0 >> 6) : 0;
  int t1 = (qb * 128 + 128) >> 6;
  int qlo = qw, qhi = qw + 31;
  for (int tt = t0; tt < t1; ++tt) {
    int kb = tt * 64;
    // ---- stage K,V tiles (block-cooperative, 8+8 calls per wave) ----
    const bf16_t* kgb = kg + (long)kb * QKV_COLS;
    const bf16_t* vgb = vg + kb;
#pragma unroll
    for (int c = 0; c < 8; ++c) {
      int rowk = (w * 8 + c) * 2 + lrK;
      gload16(kgb + rowk * QKV_COLS + ((slK ^ (rowk & 7)) * 8), ksl + c * 512);
      int rowv = (w * 8 + c) * 8 + lrV;
      gload16(vgb + rowv * SEQ + ((slV ^ (rowv & 7)) * 8), vsl + c * 512);
    }
    __syncthreads();
    bool active = !(kb > qhi || kb + 63 < qlo - (WINDOW - 1));
    if (active) {
      bool full = (kb + 63 <= qlo) && (qhi - kb <= WINDOW - 1);
      // ---- QK^T: 64 MFMA ----
      f32x4 sc[2][4] = {};
#pragma unroll
      for (int kk = 0; kk < 8; ++kk) {
        int slot = (kk * 4 + g) ^ (r16 & 7);
#pragma unroll
        for (int c = 0; c < 4; ++c) {
          bf16x8 kf = *(const bf16x8*)&Ks[(c * 16 + r16) * 256 + slot * 8];
          sc[0][c] = __builtin_amdgcn_mfma_f32_16x16x32_bf16(qf[0][kk], kf, sc[0][c], 0, 0, 0);
          sc[1][c] = __builtin_amdgcn_mfma_f32_16x16x32_bf16(qf[1][kk], kf, sc[1][c], 0, 0, 0);
        }
      }
      // ---- softcap + fixed-max softmax, P -> LDS (swizzled) ----
#pragma unroll
      for (int rf = 0; rf < 2; ++rf)
#pragma unroll
        for (int c = 0; c < 4; ++c)
#pragma unroll
          for (int r = 0; r < 4; ++r) {
            float s = sc[rf][c][r];
            float v = CAP_F * fast_tanh(s * (SCALE_F / CAP_F));
            if (!full) {
              int q = qw + rf * 16 + g * 4 + r;
              int k = kb + c * 16 + r16;
              if (!((k <= q) && (q - k < WINDOW))) v = -1e30f;
            }
            bf16_t pb = (bf16_t)__expf(v - SM_MAX);
            lsum[rf][r] += (float)pb;
            int prow = rf * 16 + g * 4 + r;
            int pbyte = prow * 128 + ((c * 32 + r16 * 2) ^ ((prow & 7) << 4));
            *(bf16_t*)((char*)pw + pbyte) = pb;
          }
      // ---- PV: 64 MFMA ----
      bf16x8 pa[2][2];
#pragma unroll
      for (int rf = 0; rf < 2; ++rf)
#pragma unroll
        for (int pk = 0; pk < 2; ++pk) {
          int prow = rf * 16 + r16;
          int pb = prow * 128 + ((pk * 64 + g * 16) ^ ((prow & 7) << 4));
          pa[rf][pk] = *(const bf16x8*)((const char*)pw + pb);
        }
#pragma unroll
      for (int dt = 0; dt < 16; ++dt)
#pragma unroll
        for (int pk = 0; pk < 2; ++pk) {
          bf16x8 vf = *(const bf16x8*)&Vs[(dt * 16 + r16) * 64 + (((pk * 4 + g) ^ (r16 & 7)) * 8)];
          acc[0][dt] = __builtin_amdgcn_mfma_f32_16x16x32_bf16(pa[0][pk], vf, acc[0][dt], 0, 0, 0);
          acc[1][dt] = __builtin_amdgcn_mfma_f32_16x16x32_bf16(pa[1][pk], vf, acc[1][dt], 0, 0, 0);
        }
    }
    __syncthreads();
  }
  // ---- normalize + write ----
  float inv[2][4];
#pragma unroll
  for (int rf = 0; rf < 2; ++rf)
#pragma unroll
    for (int r = 0; r < 4; ++r) {
      float s = lsum[rf][r];
      s += __shfl_xor(s, 1);
      s += __shfl_xor(s, 2);
      s += __shfl_xor(s, 4);
      s += __shfl_xor(s, 8);
      inv[rf][r] = 1.0f / s;
    }
#pragma unroll
  for (int rf = 0; rf < 2; ++rf)
#pragma unroll
    for (int dt = 0; dt < 16; ++dt)
#pragma unroll
      for (int r = 0; r < 4; ++r) {
        long row = qw + rf * 16 + g * 4 + r;
        attn_out[row * Q_SIZE + h * DH + dt * 16 + r16] = (bf16_t)(acc[rf][dt][r] * inv[rf][r]);
      }
}

extern "C" void kernel_launch(void* const* d_in, const int* in_sizes, int n_in,
                              void* d_out, int out_size, void* d_ws, size_t ws_size,
                              hipStream_t stream) {
  const float* hid_f  = (const float*)d_in[1];
  const float* wqkv_f = (const float*)d_in[2];
  const float* wo_f   = (const float*)d_in[3];
  float* out = (float*)d_out;
  char* ws = (char*)d_ws;
  bf16_t* qkv    = (bf16_t*)(ws);                 // 67,108,864
  bf16_t* wo_b   = (bf16_t*)(ws + 67108864);      // 29,360,128
  bf16_t* hid_b  = (bf16_t*)(ws + 96468992);      // 29,360,128
  bf16_t* wqkv_b = (bf16_t*)(ws + 125829120);     // 58,720,256
  bf16_t* attn_b = (bf16_t*)(ws + 96468992);      // alias over hid_b (dead after GEMM1)
  bf16_t* vt     = (bf16_t*)(ws + 130023424);     // alias over wqkv tail (dead after GEMM1)

  cvt_f32_to_bf16<<<7168, 256, 0, stream>>>(hid_f, hid_b, 14680064 / 8);
  cvt_f32_to_bf16<<<14336, 256, 0, stream>>>(wqkv_f, wqkv_b, 29360128 / 8);
  cvt_f32_to_bf16<<<7168, 256, 0, stream>>>(wo_f, wo_b, 14680064 / 8);
  gemm_bt<true><<<dim3(64, 32), 256, 0, stream>>>(hid_b, wqkv_b, qkv, SEQ, QKV_COLS, HIDDEN);
  rope_kernel<<<49152, 256, 0, stream>>>(qkv);
  vtrans_kernel<<<dim3(64, 32), 256, 0, stream>>>(qkv, vt);
  attn_kernel<<<512, 256, 0, stream>>>(qkv, vt, attn_b);
  gemm_bt<false><<<dim3(28, 32), 256, 0, stream>>>(attn_b, wo_b, out, SEQ, HIDDEN, Q_SIZE);
}

// Round 4
// 847.009 us; speedup vs baseline: 1.7981x; 1.3083x over previous
//
#include <hip/hip_runtime.h>
#include <hip/hip_bf16.h>

typedef __bf16 bf16_t;
typedef __bf16 bf16x8 __attribute__((ext_vector_type(8)));
typedef float f32x4 __attribute__((ext_vector_type(4)));

#define HIDDEN 3584
#define NQH 16
#define NKVH 8
#define DH 256
#define SEQ 4096
#define QKV_COLS 8192   // (NQH + 2*NKVH) * DH
#define Q_SIZE 4096     // NQH * DH
#define KV_SIZE 2048    // NKVH * DH
#define WINDOW 2048
#define SCALE_F 0.0625f // 256^-0.5
#define CAP_F 50.0f
#define SM_MAX 12.0f    // fixed softmax max; scores capped to +-50 by tanh -> always safe

__device__ __forceinline__ float fast_tanh(float x) {
  return 1.0f - 2.0f / (__expf(2.0f * x) + 1.0f);
}

__device__ __forceinline__ void gload16(const bf16_t* g, bf16_t* l) {
  __builtin_amdgcn_global_load_lds((__attribute__((address_space(1))) void*)g,
                                   (__attribute__((address_space(3))) void*)l, 16, 0, 0);
}

// ---------------- f32 -> bf16 conversion (vectorized) ----------------
__global__ __launch_bounds__(256) void cvt_f32_to_bf16(const float* __restrict__ src,
                                                       bf16_t* __restrict__ dst, long n8) {
  long i = (long)blockIdx.x * 256 + threadIdx.x;
  if (i >= n8) return;
  const float4* s4 = (const float4*)src;
  float4 a = s4[i * 2];
  float4 b = s4[i * 2 + 1];
  bf16x8 o;
  o[0] = (bf16_t)a.x; o[1] = (bf16_t)a.y; o[2] = (bf16_t)a.z; o[3] = (bf16_t)a.w;
  o[4] = (bf16_t)b.x; o[5] = (bf16_t)b.y; o[6] = (bf16_t)b.z; o[7] = (bf16_t)b.w;
  *(bf16x8*)(dst + i * 8) = o;
}

// ---------------- bf16 GEMM, C[M,N] = A[M,K] * B[N,K]^T ----------------
// m97 structure: 128x128 tile, BK=32, global_load_lds width-16 staging with
// source pre-swizzle (phys slot s holds logical chunk s^(row&3)).
template <bool OUT_BF16>
__global__ __launch_bounds__(256) void gemm_bt(const bf16_t* __restrict__ A,
                                               const bf16_t* __restrict__ B,
                                               void* __restrict__ Cout,
                                               int M, int N, int K) {
  __shared__ bf16_t As[128 * 32];
  __shared__ bf16_t Bs[128 * 32];
  int t = threadIdx.x;
  int lane = t & 63, w = t >> 6;
  int wr = w >> 1, wc = w & 1;
  int r16 = lane & 15, g = lane >> 4;
  long bm = (long)blockIdx.y * 128, bn = (long)blockIdx.x * 128;
  int srow = w * 32 + (lane >> 2);
  int ch = (lane & 3) ^ ((lane >> 2) & 3);
  const bf16_t* gA0 = A + (bm + srow) * K + ch * 8;
  const bf16_t* gA1 = gA0 + 16 * K;
  const bf16_t* gB0 = B + (bn + srow) * K + ch * 8;
  const bf16_t* gB1 = gB0 + 16 * K;
  bf16_t* lA = As + w * 1024;
  bf16_t* lB = Bs + w * 1024;
  int xsl = (g ^ (r16 & 3)) * 8;
  f32x4 acc[4][4] = {};
  for (int k0 = 0; k0 < K; k0 += 32) {
    gload16(gA0, lA); gload16(gA1, lA + 512);
    gload16(gB0, lB); gload16(gB1, lB + 512);
    gA0 += 32; gA1 += 32; gB0 += 32; gB1 += 32;
    __syncthreads();
    bf16x8 af[4], bfr[4];
#pragma unroll
    for (int i = 0; i < 4; ++i) af[i] = *(const bf16x8*)&As[(wr * 64 + i * 16 + r16) * 32 + xsl];
#pragma unroll
    for (int j = 0; j < 4; ++j) bfr[j] = *(const bf16x8*)&Bs[(wc * 64 + j * 16 + r16) * 32 + xsl];
#pragma unroll
    for (int i = 0; i < 4; ++i)
#pragma unroll
      for (int j = 0; j < 4; ++j)
        acc[i][j] = __builtin_amdgcn_mfma_f32_16x16x32_bf16(af[i], bfr[j], acc[i][j], 0, 0, 0);
    __syncthreads();
  }
#pragma unroll
  for (int i = 0; i < 4; ++i)
#pragma unroll
    for (int j = 0; j < 4; ++j)
#pragma unroll
      for (int r = 0; r < 4; ++r) {
        long row = bm + wr * 64 + i * 16 + g * 4 + r;
        long col = bn + wc * 64 + j * 16 + r16;
        if (OUT_BF16) ((bf16_t*)Cout)[row * N + col] = (bf16_t)acc[i][j][r];
        else          ((float*)Cout)[row * N + col]  = acc[i][j][r];
      }
}

// ---------------- RoPE (neox), in-place on q,k of qkv ----------------
__global__ __launch_bounds__(256) void rope_kernel(bf16_t* __restrict__ qkv) {
  long idx = (long)blockIdx.x * 256 + threadIdx.x;
  int i = (int)(idx & 127);
  long rem = idx >> 7;
  int head = (int)(rem % 24);
  int s = (int)(rem / 24);
  int base = head < NQH ? head * DH : Q_SIZE + (head - NQH) * DH;
  long p1 = (long)s * QKV_COLS + base + i;
  long p2 = p1 + 128;
  float x1 = (float)qkv[p1], x2 = (float)qkv[p2];
  float inv_freq = exp2f((float)i * -0.10381025296522976f);
  float fr = (float)s * inv_freq;
  float sn, cs;
  sincosf(fr, &sn, &cs);
  qkv[p1] = (bf16_t)(x1 * cs - x2 * sn);
  qkv[p2] = (bf16_t)(x2 * cs + x1 * sn);
}

// ---------------- V transpose: vt[kv_col][s] = qkv[s][6144 + kv_col] ----------------
__global__ __launch_bounds__(256) void vtrans_kernel(const bf16_t* __restrict__ qkv,
                                                     bf16_t* __restrict__ vt) {
  __shared__ bf16_t tile[64][72];
  int t = threadIdx.x;
  long s0 = (long)blockIdx.x * 64;
  long c0 = (long)blockIdx.y * 64;
#pragma unroll
  for (int it = 0; it < 2; ++it) {
    int u = t + it * 256;
    int sr = u >> 3, ch = u & 7;
    bf16x8 v = *(const bf16x8*)&qkv[(s0 + sr) * QKV_COLS + (Q_SIZE + KV_SIZE) + c0 + ch * 8];
    *(bf16x8*)&tile[sr][ch * 8] = v;
  }
  __syncthreads();
#pragma unroll
  for (int it = 0; it < 2; ++it) {
    int u = t + it * 256;
    int cr = u >> 3, ch = u & 7;
    bf16x8 o;
#pragma unroll
    for (int j = 0; j < 8; ++j) o[j] = tile[ch * 8 + j][cr];
    *(bf16x8*)&vt[(c0 + cr) * SEQ + s0 + ch * 8] = o;
  }
}

// ---------------- flash attention: softcap + sliding window + GQA ----------------
// Block: 128 q rows x 1 head, 8 waves x 16 rows (512 thr). 64-key tiles.
// K tile [64][256] and V^T tile [256][64] staged via global_load_lds with
// pre-swizzled source (phys 16B slot s holds logical chunk s^(row&7)).
// Fixed-max softmax (scores in [-50,50] by softcap): p = exp(v - 12).
// Per-wave regs: qf 32 + acc 64 + temps ~ 160 VGPR -> no spill (round-3 bug).
__global__ __launch_bounds__(512, 2) void attn_kernel(const bf16_t* __restrict__ qkv,
                                                      const bf16_t* __restrict__ vt,
                                                      bf16_t* __restrict__ attn_out) {
  __shared__ bf16_t Ks[64 * 256];   // 32 KB
  __shared__ bf16_t Vs[256 * 64];   // 32 KB
  __shared__ bf16_t Pl[8 * 1024];   // 16 KB, 2KB per wave, XOR-swizzled
  int t = threadIdx.x;
  int lane = t & 63, w = t >> 6;
  int r16 = lane & 15, g = lane >> 4;
  // XCD swizzle: blocks with same kv head land on same XCD's L2
  int bid = blockIdx.x;
  int swz = (bid & 7) * 64 + (bid >> 3);
  int h = swz >> 5;
  int qb = swz & 31;
  int kvh = h >> 1;
  int qw = qb * 128 + w * 16;       // wave's first q row
  bf16x8 qf[8];
  long qoff = (long)(qw + r16) * QKV_COLS + h * DH + g * 8;
#pragma unroll
  for (int kk = 0; kk < 8; ++kk) qf[kk] = *(const bf16x8*)&qkv[qoff + kk * 32];
  f32x4 acc[16] = {};
  float lsum[4] = {};
  int lrK = lane >> 5, slK = lane & 31;  // K stage: 2 rows/call, 32 slots/row
  int lrV = lane >> 3, slV = lane & 7;   // V stage: 8 rows/call, 8 slots/row
  const bf16_t* kg = qkv + Q_SIZE + (long)kvh * DH;
  const bf16_t* vg = vt + (long)kvh * DH * SEQ;
  bf16_t* ksl = Ks + w * 2048;
  bf16_t* vsl = Vs + w * 2048;
  bf16_t* pw = Pl + w * 1024;
  int t0 = qb * 128 - (WINDOW - 1);
  t0 = t0 > 0 ? (t0 >> 6) : 0;
  int t1 = (qb * 128 + 128) >> 6;
  int qlo = qw, qhi = qw + 15;
  for (int tt = t0; tt < t1; ++tt) {
    int kb = tt * 64;
    // ---- stage K,V tiles (block-cooperative, 4+4 calls per wave) ----
    const bf16_t* kgb = kg + (long)kb * QKV_COLS;
    const bf16_t* vgb = vg + kb;
#pragma unroll
    for (int c = 0; c < 4; ++c) {
      int rowk = w * 8 + c * 2 + lrK;
      gload16(kgb + rowk * QKV_COLS + ((slK ^ (rowk & 7)) * 8), ksl + c * 512);
      int rowv = w * 32 + c * 8 + lrV;
      gload16(vgb + rowv * SEQ + ((slV ^ (rowv & 7)) * 8), vsl + c * 512);
    }
    __syncthreads();
    bool active = !(kb > qhi || kb + 63 < qlo - (WINDOW - 1));
    if (active) {
      bool full = (kb + 63 <= qlo) && (qhi - kb <= WINDOW - 1);
      // ---- QK^T: 32 MFMA ----
      f32x4 sc[4] = {};
#pragma unroll
      for (int kk = 0; kk < 8; ++kk) {
        int slot = (kk * 4 + g) ^ (r16 & 7);
#pragma unroll
        for (int c = 0; c < 4; ++c) {
          bf16x8 kf = *(const bf16x8*)&Ks[(c * 16 + r16) * 256 + slot * 8];
          sc[c] = __builtin_amdgcn_mfma_f32_16x16x32_bf16(qf[kk], kf, sc[c], 0, 0, 0);
        }
      }
      // ---- softcap + fixed-max softmax, P -> LDS (swizzled) ----
#pragma unroll
      for (int c = 0; c < 4; ++c)
#pragma unroll
        for (int r = 0; r < 4; ++r) {
          float s = sc[c][r];
          float v = CAP_F * fast_tanh(s * (SCALE_F / CAP_F));
          if (!full) {
            int q = qw + g * 4 + r;
            int k = kb + c * 16 + r16;
            if (!((k <= q) && (q - k < WINDOW))) v = -1e30f;
          }
          bf16_t pb = (bf16_t)__expf(v - SM_MAX);
          lsum[r] += (float)pb;
          int prow = g * 4 + r;
          int pbyte = prow * 128 + ((c * 32 + r16 * 2) ^ ((prow & 7) << 4));
          *(bf16_t*)((char*)pw + pbyte) = pb;
        }
      // ---- PV: 32 MFMA ----
      bf16x8 pa[2];
#pragma unroll
      for (int pk = 0; pk < 2; ++pk) {
        int pb = r16 * 128 + ((pk * 64 + g * 16) ^ ((r16 & 7) << 4));
        pa[pk] = *(const bf16x8*)((const char*)pw + pb);
      }
#pragma unroll
      for (int dt = 0; dt < 16; ++dt)
#pragma unroll
        for (int pk = 0; pk < 2; ++pk) {
          bf16x8 vf = *(const bf16x8*)&Vs[(dt * 16 + r16) * 64 + (((pk * 4 + g) ^ (r16 & 7)) * 8)];
          acc[dt] = __builtin_amdgcn_mfma_f32_16x16x32_bf16(pa[pk], vf, acc[dt], 0, 0, 0);
        }
    }
    __syncthreads();
  }
  // ---- normalize + write ----
  float inv[4];
#pragma unroll
  for (int r = 0; r < 4; ++r) {
    float s = lsum[r];
    s += __shfl_xor(s, 1);
    s += __shfl_xor(s, 2);
    s += __shfl_xor(s, 4);
    s += __shfl_xor(s, 8);
    inv[r] = 1.0f / s;
  }
#pragma unroll
  for (int dt = 0; dt < 16; ++dt)
#pragma unroll
    for (int r = 0; r < 4; ++r) {
      long row = qw + g * 4 + r;
      attn_out[row * Q_SIZE + h * DH + dt * 16 + r16] = (bf16_t)(acc[dt][r] * inv[r]);
    }
}

extern "C" void kernel_launch(void* const* d_in, const int* in_sizes, int n_in,
                              void* d_out, int out_size, void* d_ws, size_t ws_size,
                              hipStream_t stream) {
  const float* hid_f  = (const float*)d_in[1];
  const float* wqkv_f = (const float*)d_in[2];
  const float* wo_f   = (const float*)d_in[3];
  float* out = (float*)d_out;
  char* ws = (char*)d_ws;
  bf16_t* qkv    = (bf16_t*)(ws);                 // 67,108,864
  bf16_t* wo_b   = (bf16_t*)(ws + 67108864);      // 29,360,128
  bf16_t* hid_b  = (bf16_t*)(ws + 96468992);      // 29,360,128
  bf16_t* wqkv_b = (bf16_t*)(ws + 125829120);     // 58,720,256
  bf16_t* attn_b = (bf16_t*)(ws + 96468992);      // alias over hid_b (dead after GEMM1)
  bf16_t* vt     = (bf16_t*)(ws + 130023424);     // alias over wqkv tail (dead after GEMM1)

  cvt_f32_to_bf16<<<7168, 256, 0, stream>>>(hid_f, hid_b, 14680064 / 8);
  cvt_f32_to_bf16<<<14336, 256, 0, stream>>>(wqkv_f, wqkv_b, 29360128 / 8);
  cvt_f32_to_bf16<<<7168, 256, 0, stream>>>(wo_f, wo_b, 14680064 / 8);
  gemm_bt<true><<<dim3(64, 32), 256, 0, stream>>>(hid_b, wqkv_b, qkv, SEQ, QKV_COLS, HIDDEN);
  rope_kernel<<<49152, 256, 0, stream>>>(qkv);
  vtrans_kernel<<<dim3(64, 32), 256, 0, stream>>>(qkv, vt);
  attn_kernel<<<512, 512, 0, stream>>>(qkv, vt, attn_b);
  gemm_bt<false><<<dim3(28, 32), 256, 0, stream>>>(attn_b, wo_b, out, SEQ, HIDDEN, Q_SIZE);
}

// Round 6
// 678.812 us; speedup vs baseline: 2.2436x; 1.2478x over previous
//
#include <hip/hip_runtime.h>
#include <hip/hip_bf16.h>

typedef __bf16 bf16_t;
typedef __bf16 bf16x8 __attribute__((ext_vector_type(8)));
typedef float f32x4 __attribute__((ext_vector_type(4)));

#define HIDDEN 3584
#define NQH 16
#define NKVH 8
#define DH 256
#define SEQ 4096
#define QKV_COLS 8192   // (NQH + 2*NKVH) * DH
#define Q_SIZE 4096     // NQH * DH
#define KV_SIZE 2048    // NKVH * DH
#define WINDOW 2048
#define SCALE_F 0.0625f // 256^-0.5
#define CAP_F 50.0f
#define SM_MAX 12.0f    // fixed softmax max; scores capped to +-50 by tanh -> always safe

__device__ __forceinline__ float fast_tanh(float x) {
  return 1.0f - 2.0f / (__expf(2.0f * x) + 1.0f);
}

__device__ __forceinline__ void gload16(const bf16_t* g, bf16_t* l) {
  __builtin_amdgcn_global_load_lds((__attribute__((address_space(1))) void*)g,
                                   (__attribute__((address_space(3))) void*)l, 16, 0, 0);
}

// ---------------- f32 -> bf16 conversion (vectorized) ----------------
__global__ __launch_bounds__(256) void cvt_f32_to_bf16(const float* __restrict__ src,
                                                       bf16_t* __restrict__ dst, long n8) {
  long i = (long)blockIdx.x * 256 + threadIdx.x;
  if (i >= n8) return;
  const float4* s4 = (const float4*)src;
  float4 a = s4[i * 2];
  float4 b = s4[i * 2 + 1];
  bf16x8 o;
  o[0] = (bf16_t)a.x; o[1] = (bf16_t)a.y; o[2] = (bf16_t)a.z; o[3] = (bf16_t)a.w;
  o[4] = (bf16_t)b.x; o[5] = (bf16_t)b.y; o[6] = (bf16_t)b.z; o[7] = (bf16_t)b.w;
  *(bf16x8*)(dst + i * 8) = o;
}

// ---------------- bf16 GEMM, C[4096,N] = A[4096,K] * B[N,K]^T ----------------
// 256x256 tile, BK=32, 8 waves (2Mx4N), 4-deep LDS pipeline (4 x 32KB bufs),
// counted vmcnt(8) before tile-end barrier (per-wave certify -> barrier -> all
// waves' loads landed), setprio around MFMA clusters, conflict-free XOR LDS
// (2 M-rows packed per 128B line, phys slot = logical ^ (ldsrow&7)).
#define TILE(T, WSTR, STAGE)                                                                \
  {                                                                                         \
    char* buf = lds + ((T) & 3) * 32768;                                                    \
    bf16x8 af[8], b0, b1, b2, b3;                                                           \
    _Pragma("unroll")                                                                       \
    for (int i = 0; i < 8; ++i) af[i] = *(const bf16x8*)(buf + aoff + i * 1024);            \
    b0 = *(const bf16x8*)(buf + boff);                                                      \
    b1 = *(const bf16x8*)(buf + boff + 1024);                                               \
    if (STAGE) {                                                                            \
      char* d = lds + (((T) + 3) & 3) * 32768;                                              \
      gload16(sA0 + ((T) + 3) * 32, (bf16_t*)(d + sdst0));                                  \
      gload16(sA1 + ((T) + 3) * 32, (bf16_t*)(d + 8192 + sdst0));                           \
    }                                                                                       \
    __builtin_amdgcn_s_setprio(1);                                                          \
    _Pragma("unroll")                                                                       \
    for (int i = 0; i < 8; ++i) {                                                           \
      acc[i][0] = __builtin_amdgcn_mfma_f32_16x16x32_bf16(af[i], b0, acc[i][0], 0, 0, 0);   \
      acc[i][1] = __builtin_amdgcn_mfma_f32_16x16x32_bf16(af[i], b1, acc[i][1], 0, 0, 0);   \
    }                                                                                       \
    __builtin_amdgcn_s_setprio(0);                                                          \
    __builtin_amdgcn_s_barrier();                                                           \
    b2 = *(const bf16x8*)(buf + boff + 2048);                                               \
    b3 = *(const bf16x8*)(buf + boff + 3072);                                               \
    if (STAGE) {                                                                            \
      char* d = lds + (((T) + 3) & 3) * 32768;                                              \
      gload16(sB0 + ((T) + 3) * 32, (bf16_t*)(d + 16384 + sdst0));                          \
      gload16(sB1 + ((T) + 3) * 32, (bf16_t*)(d + 24576 + sdst0));                          \
    }                                                                                       \
    __builtin_amdgcn_s_setprio(1);                                                          \
    _Pragma("unroll")                                                                       \
    for (int i = 0; i < 8; ++i) {                                                           \
      acc[i][2] = __builtin_amdgcn_mfma_f32_16x16x32_bf16(af[i], b2, acc[i][2], 0, 0, 0);   \
      acc[i][3] = __builtin_amdgcn_mfma_f32_16x16x32_bf16(af[i], b3, acc[i][3], 0, 0, 0);   \
    }                                                                                       \
    __builtin_amdgcn_s_setprio(0);                                                          \
    asm volatile("s_waitcnt vmcnt(" WSTR ")" ::: "memory");                                 \
    __builtin_amdgcn_s_barrier();                                                           \
  }

template <int K, bool OUT_BF16>
__global__ __launch_bounds__(512, 2) void gemm_bt(const bf16_t* __restrict__ A,
                                                  const bf16_t* __restrict__ B,
                                                  void* __restrict__ Cout, int N) {
  constexpr int NT = K / 32;
  __shared__ char lds[4 * 32768];
  int tid = threadIdx.x;
  int lane = tid & 63, w = tid >> 6;
  int wm = w >> 2, wn = w & 3;
  int r16 = lane & 15, g = lane >> 4;
  // block swizzle: xcd (bid&7) owns M-pair {2x, 2x+1}, sweeps N for L2 reuse
  int bid = blockIdx.x;
  long bm = (long)((bid & 7) * 2 + ((bid >> 3) & 1)) * 256;
  long bn = (long)(bid >> 4) * 256;
  // ds_read constants (2 M-rows per 128B LDS line, XOR slot swizzle)
  int ro = r16 >> 1;
  int asl = ((g + ((r16 & 1) << 2)) ^ ro) << 4;
  int aoff = wm * 8192 + ro * 128 + asl;
  int boff = 16384 + wn * 4096 + ro * 128 + asl;
  // staging constants: lane -> (lds row = lane>>3, phys slot = lane&7)
  int slr = lane >> 3;
  int lc = (lane & 7) ^ slr;            // logical chunk held by this lane's slot
  int kc8 = (lc & 3) * 8;
  long mr0 = (long)(w * 8 + slr) * 2 + (lc >> 2);
  long mr1 = mr0 + 128;
  const bf16_t* sA0 = A + (bm + mr0) * K + kc8;
  const bf16_t* sA1 = A + (bm + mr1) * K + kc8;
  const bf16_t* sB0 = B + (bn + mr0) * K + kc8;
  const bf16_t* sB1 = B + (bn + mr1) * K + kc8;
  int sdst0 = w * 1024;
  f32x4 acc[8][4] = {};
  // prologue: stage tiles 0,1,2
#pragma unroll
  for (int u = 0; u < 3; ++u) {
    char* d = lds + u * 32768;
    gload16(sA0 + u * 32, (bf16_t*)(d + sdst0));
    gload16(sA1 + u * 32, (bf16_t*)(d + 8192 + sdst0));
    gload16(sB0 + u * 32, (bf16_t*)(d + 16384 + sdst0));
    gload16(sB1 + u * 32, (bf16_t*)(d + 24576 + sdst0));
  }
  asm volatile("s_waitcnt vmcnt(8)" ::: "memory");
  __builtin_amdgcn_s_barrier();
  int t = 0;
  for (; t < NT - 3; ++t) TILE(t, "8", true);
  TILE(t, "4", false); ++t;
  TILE(t, "0", false); ++t;
  TILE(t, "0", false);
#pragma unroll
  for (int i = 0; i < 8; ++i)
#pragma unroll
    for (int j = 0; j < 4; ++j)
#pragma unroll
      for (int r = 0; r < 4; ++r) {
        long row = bm + wm * 128 + i * 16 + g * 4 + r;
        long col = bn + wn * 64 + j * 16 + r16;
        if (OUT_BF16) ((bf16_t*)Cout)[row * N + col] = (bf16_t)acc[i][j][r];
        else          ((float*)Cout)[row * N + col]  = acc[i][j][r];
      }
}

// ---------------- RoPE (neox), in-place on q,k of qkv ----------------
__global__ __launch_bounds__(256) void rope_kernel(bf16_t* __restrict__ qkv) {
  long idx = (long)blockIdx.x * 256 + threadIdx.x;
  int i = (int)(idx & 127);
  long rem = idx >> 7;
  int head = (int)(rem % 24);
  int s = (int)(rem / 24);
  int base = head < NQH ? head * DH : Q_SIZE + (head - NQH) * DH;
  long p1 = (long)s * QKV_COLS + base + i;
  long p2 = p1 + 128;
  float x1 = (float)qkv[p1], x2 = (float)qkv[p2];
  float inv_freq = exp2f((float)i * -0.10381025296522976f);
  float fr = (float)s * inv_freq;
  float sn, cs;
  sincosf(fr, &sn, &cs);
  qkv[p1] = (bf16_t)(x1 * cs - x2 * sn);
  qkv[p2] = (bf16_t)(x2 * cs + x1 * sn);
}

// ---------------- V transpose: vt[kv_col][s] = qkv[s][6144 + kv_col] ----------------
__global__ __launch_bounds__(256) void vtrans_kernel(const bf16_t* __restrict__ qkv,
                                                     bf16_t* __restrict__ vt) {
  __shared__ bf16_t tile[64][72];
  int t = threadIdx.x;
  long s0 = (long)blockIdx.x * 64;
  long c0 = (long)blockIdx.y * 64;
#pragma unroll
  for (int it = 0; it < 2; ++it) {
    int u = t + it * 256;
    int sr = u >> 3, ch = u & 7;
    bf16x8 v = *(const bf16x8*)&qkv[(s0 + sr) * QKV_COLS + (Q_SIZE + KV_SIZE) + c0 + ch * 8];
    *(bf16x8*)&tile[sr][ch * 8] = v;
  }
  __syncthreads();
#pragma unroll
  for (int it = 0; it < 2; ++it) {
    int u = t + it * 256;
    int cr = u >> 3, ch = u & 7;
    bf16x8 o;
#pragma unroll
    for (int j = 0; j < 8; ++j) o[j] = tile[ch * 8 + j][cr];
    *(bf16x8*)&vt[(c0 + cr) * SEQ + s0 + ch * 8] = o;
  }
}

// ---------------- flash attention: softcap + sliding window + GQA ----------------
__global__ __launch_bounds__(512, 2) void attn_kernel(const bf16_t* __restrict__ qkv,
                                                      const bf16_t* __restrict__ vt,
                                                      bf16_t* __restrict__ attn_out) {
  __shared__ bf16_t Ks[64 * 256];   // 32 KB
  __shared__ bf16_t Vs[256 * 64];   // 32 KB
  __shared__ bf16_t Pl[8 * 1024];   // 16 KB, 2KB per wave, XOR-swizzled
  int t = threadIdx.x;
  int lane = t & 63, w = t >> 6;
  int r16 = lane & 15, g = lane >> 4;
  int bid = blockIdx.x;
  int swz = (bid & 7) * 64 + (bid >> 3);
  int h = swz >> 5;
  int qb = swz & 31;
  int kvh = h >> 1;
  int qw = qb * 128 + w * 16;
  bf16x8 qf[8];
  long qoff = (long)(qw + r16) * QKV_COLS + h * DH + g * 8;
#pragma unroll
  for (int kk = 0; kk < 8; ++kk) qf[kk] = *(const bf16x8*)&qkv[qoff + kk * 32];
  f32x4 acc[16] = {};
  float lsum[4] = {};
  int lrK = lane >> 5, slK = lane & 31;
  int lrV = lane >> 3, slV = lane & 7;
  const bf16_t* kg = qkv + Q_SIZE + (long)kvh * DH;
  const bf16_t* vg = vt + (long)kvh * DH * SEQ;
  bf16_t* ksl = Ks + w * 2048;
  bf16_t* vsl = Vs + w * 2048;
  bf16_t* pw = Pl + w * 1024;
  int t0 = qb * 128 - (WINDOW - 1);
  t0 = t0 > 0 ? (t0 >> 6) : 0;
  int t1 = (qb * 128 + 128) >> 6;
  int qlo = qw, qhi = qw + 15;
  for (int tt = t0; tt < t1; ++tt) {
    int kb = tt * 64;
    const bf16_t* kgb = kg + (long)kb * QKV_COLS;
    const bf16_t* vgb = vg + kb;
#pragma unroll
    for (int c = 0; c < 4; ++c) {
      int rowk = w * 8 + c * 2 + lrK;
      gload16(kgb + rowk * QKV_COLS + ((slK ^ (rowk & 7)) * 8), ksl + c * 512);
      int rowv = w * 32 + c * 8 + lrV;
      gload16(vgb + rowv * SEQ + ((slV ^ (rowv & 7)) * 8), vsl + c * 512);
    }
    __syncthreads();
    bool active = !(kb > qhi || kb + 63 < qlo - (WINDOW - 1));
    if (active) {
      bool full = (kb + 63 <= qlo) && (qhi - kb <= WINDOW - 1);
      f32x4 sc[4] = {};
#pragma unroll
      for (int kk = 0; kk < 8; ++kk) {
        int slot = (kk * 4 + g) ^ (r16 & 7);
#pragma unroll
        for (int c = 0; c < 4; ++c) {
          bf16x8 kf = *(const bf16x8*)&Ks[(c * 16 + r16) * 256 + slot * 8];
          sc[c] = __builtin_amdgcn_mfma_f32_16x16x32_bf16(qf[kk], kf, sc[c], 0, 0, 0);
        }
      }
#pragma unroll
      for (int c = 0; c < 4; ++c)
#pragma unroll
        for (int r = 0; r < 4; ++r) {
          float s = sc[c][r];
          float v = CAP_F * fast_tanh(s * (SCALE_F / CAP_F));
          if (!full) {
            int q = qw + g * 4 + r;
            int k = kb + c * 16 + r16;
            if (!((k <= q) && (q - k < WINDOW))) v = -1e30f;
          }
          bf16_t pb = (bf16_t)__expf(v - SM_MAX);
          lsum[r] += (float)pb;
          int prow = g * 4 + r;
          int pbyte = prow * 128 + ((c * 32 + r16 * 2) ^ ((prow & 7) << 4));
          *(bf16_t*)((char*)pw + pbyte) = pb;
        }
      bf16x8 pa[2];
#pragma unroll
      for (int pk = 0; pk < 2; ++pk) {
        int pb = r16 * 128 + ((pk * 64 + g * 16) ^ ((r16 & 7) << 4));
        pa[pk] = *(const bf16x8*)((const char*)pw + pb);
      }
#pragma unroll
      for (int dt = 0; dt < 16; ++dt)
#pragma unroll
        for (int pk = 0; pk < 2; ++pk) {
          bf16x8 vf = *(const bf16x8*)&Vs[(dt * 16 + r16) * 64 + (((pk * 4 + g) ^ (r16 & 7)) * 8)];
          acc[dt] = __builtin_amdgcn_mfma_f32_16x16x32_bf16(pa[pk], vf, acc[dt], 0, 0, 0);
        }
    }
    __syncthreads();
  }
  float inv[4];
#pragma unroll
  for (int r = 0; r < 4; ++r) {
    float s = lsum[r];
    s += __shfl_xor(s, 1);
    s += __shfl_xor(s, 2);
    s += __shfl_xor(s, 4);
    s += __shfl_xor(s, 8);
    inv[r] = 1.0f / s;
  }
#pragma unroll
  for (int dt = 0; dt < 16; ++dt)
#pragma unroll
    for (int r = 0; r < 4; ++r) {
      long row = qw + g * 4 + r;
      attn_out[row * Q_SIZE + h * DH + dt * 16 + r16] = (bf16_t)(acc[dt][r] * inv[r]);
    }
}

extern "C" void kernel_launch(void* const* d_in, const int* in_sizes, int n_in,
                              void* d_out, int out_size, void* d_ws, size_t ws_size,
                              hipStream_t stream) {
  const float* hid_f  = (const float*)d_in[1];
  const float* wqkv_f = (const float*)d_in[2];
  const float* wo_f   = (const float*)d_in[3];
  float* out = (float*)d_out;
  char* ws = (char*)d_ws;
  bf16_t* qkv    = (bf16_t*)(ws);                 // 67,108,864
  bf16_t* wo_b   = (bf16_t*)(ws + 67108864);      // 29,360,128
  bf16_t* hid_b  = (bf16_t*)(ws + 96468992);      // 29,360,128
  bf16_t* wqkv_b = (bf16_t*)(ws + 125829120);     // 58,720,256
  bf16_t* attn_b = (bf16_t*)(ws + 96468992);      // alias over hid_b (dead after GEMM1)
  bf16_t* vt     = (bf16_t*)(ws + 130023424);     // alias over wqkv tail (dead after GEMM1)

  cvt_f32_to_bf16<<<7168, 256, 0, stream>>>(hid_f, hid_b, 14680064 / 8);
  cvt_f32_to_bf16<<<14336, 256, 0, stream>>>(wqkv_f, wqkv_b, 29360128 / 8);
  cvt_f32_to_bf16<<<7168, 256, 0, stream>>>(wo_f, wo_b, 14680064 / 8);
  gemm_bt<HIDDEN, true><<<512, 512, 0, stream>>>(hid_b, wqkv_b, qkv, QKV_COLS);
  rope_kernel<<<49152, 256, 0, stream>>>(qkv);
  vtrans_kernel<<<dim3(64, 32), 256, 0, stream>>>(qkv, vt);
  attn_kernel<<<512, 512, 0, stream>>>(qkv, vt, attn_b);
  gemm_bt<Q_SIZE, false><<<224, 512, 0, stream>>>(attn_b, wo_b, out, HIDDEN);
}

// Round 8
// 607.102 us; speedup vs baseline: 2.5086x; 1.1181x over previous
//
#include <hip/hip_runtime.h>
#include <hip/hip_bf16.h>

typedef __bf16 bf16_t;
typedef __bf16 bf16x4 __attribute__((ext_vector_type(4)));
typedef __bf16 bf16x8 __attribute__((ext_vector_type(8)));
typedef float f32x4 __attribute__((ext_vector_type(4)));

#define HIDDEN 3584
#define NQH 16
#define NKVH 8
#define DH 256
#define SEQ 4096
#define QKV_COLS 8192   // (NQH + 2*NKVH) * DH
#define Q_SIZE 4096     // NQH * DH
#define KV_SIZE 2048    // NKVH * DH
#define WINDOW 2048
#define SCALE_F 0.0625f // 256^-0.5
#define CAP_F 50.0f

__device__ __forceinline__ void gload16(const bf16_t* g, bf16_t* l) {
  __builtin_amdgcn_global_load_lds((__attribute__((address_space(1))) void*)g,
                                   (__attribute__((address_space(3))) void*)l, 16, 0, 0);
}

// ---------------- f32 -> bf16 conversion (vectorized) ----------------
__global__ __launch_bounds__(256) void cvt_f32_to_bf16(const float* __restrict__ src,
                                                       bf16_t* __restrict__ dst, long n8) {
  long i = (long)blockIdx.x * 256 + threadIdx.x;
  if (i >= n8) return;
  const float4* s4 = (const float4*)src;
  float4 a = s4[i * 2];
  float4 b = s4[i * 2 + 1];
  bf16x8 o;
  o[0] = (bf16_t)a.x; o[1] = (bf16_t)a.y; o[2] = (bf16_t)a.z; o[3] = (bf16_t)a.w;
  o[4] = (bf16_t)b.x; o[5] = (bf16_t)b.y; o[6] = (bf16_t)b.z; o[7] = (bf16_t)b.w;
  *(bf16x8*)(dst + i * 8) = o;
}

// ---------------- bf16 GEMM, C[4096,N] = A[4096,K] * B[N,K]^T ----------------
// 256x256 tile, BK=32, 8 waves (2Mx4N), 4-deep LDS pipeline, counted vmcnt.
#define TILE(T, WSTR, STAGE)                                                                \
  {                                                                                         \
    char* buf = lds + ((T) & 3) * 32768;                                                    \
    bf16x8 af[8], b0, b1, b2, b3;                                                           \
    _Pragma("unroll")                                                                       \
    for (int i = 0; i < 8; ++i) af[i] = *(const bf16x8*)(buf + aoff + i * 1024);            \
    b0 = *(const bf16x8*)(buf + boff);                                                      \
    b1 = *(const bf16x8*)(buf + boff + 1024);                                               \
    if (STAGE) {                                                                            \
      char* d = lds + (((T) + 3) & 3) * 32768;                                              \
      gload16(sA0 + ((T) + 3) * 32, (bf16_t*)(d + sdst0));                                  \
      gload16(sA1 + ((T) + 3) * 32, (bf16_t*)(d + 8192 + sdst0));                           \
    }                                                                                       \
    __builtin_amdgcn_s_setprio(1);                                                          \
    _Pragma("unroll")                                                                       \
    for (int i = 0; i < 8; ++i) {                                                           \
      acc[i][0] = __builtin_amdgcn_mfma_f32_16x16x32_bf16(af[i], b0, acc[i][0], 0, 0, 0);   \
      acc[i][1] = __builtin_amdgcn_mfma_f32_16x16x32_bf16(af[i], b1, acc[i][1], 0, 0, 0);   \
    }                                                                                       \
    __builtin_amdgcn_s_setprio(0);                                                          \
    __builtin_amdgcn_s_barrier();                                                           \
    b2 = *(const bf16x8*)(buf + boff + 2048);                                               \
    b3 = *(const bf16x8*)(buf + boff + 3072);                                               \
    if (STAGE) {                                                                            \
      char* d = lds + (((T) + 3) & 3) * 32768;                                              \
      gload16(sB0 + ((T) + 3) * 32, (bf16_t*)(d + 16384 + sdst0));                          \
      gload16(sB1 + ((T) + 3) * 32, (bf16_t*)(d + 24576 + sdst0));                          \
    }                                                                                       \
    __builtin_amdgcn_s_setprio(1);                                                          \
    _Pragma("unroll")                                                                       \
    for (int i = 0; i < 8; ++i) {                                                           \
      acc[i][2] = __builtin_amdgcn_mfma_f32_16x16x32_bf16(af[i], b2, acc[i][2], 0, 0, 0);   \
      acc[i][3] = __builtin_amdgcn_mfma_f32_16x16x32_bf16(af[i], b3, acc[i][3], 0, 0, 0);   \
    }                                                                                       \
    __builtin_amdgcn_s_setprio(0);                                                          \
    asm volatile("s_waitcnt vmcnt(" WSTR ")" ::: "memory");                                 \
    __builtin_amdgcn_s_barrier();                                                           \
  }

template <int K, bool OUT_BF16>
__global__ __launch_bounds__(512, 2) void gemm_bt(const bf16_t* __restrict__ A,
                                                  const bf16_t* __restrict__ B,
                                                  void* __restrict__ Cout, int N) {
  constexpr int NT = K / 32;
  __shared__ char lds[4 * 32768];
  int tid = threadIdx.x;
  int lane = tid & 63, w = tid >> 6;
  int wm = w >> 2, wn = w & 3;
  int r16 = lane & 15, g = lane >> 4;
  int bid = blockIdx.x;
  long bm = (long)((bid & 7) * 2 + ((bid >> 3) & 1)) * 256;
  long bn = (long)(bid >> 4) * 256;
  int ro = r16 >> 1;
  int asl = ((g + ((r16 & 1) << 2)) ^ ro) << 4;
  int aoff = wm * 8192 + ro * 128 + asl;
  int boff = 16384 + wn * 4096 + ro * 128 + asl;
  int slr = lane >> 3;
  int lc = (lane & 7) ^ slr;
  int kc8 = (lc & 3) * 8;
  long mr0 = (long)(w * 8 + slr) * 2 + (lc >> 2);
  long mr1 = mr0 + 128;
  const bf16_t* sA0 = A + (bm + mr0) * K + kc8;
  const bf16_t* sA1 = A + (bm + mr1) * K + kc8;
  const bf16_t* sB0 = B + (bn + mr0) * K + kc8;
  const bf16_t* sB1 = B + (bn + mr1) * K + kc8;
  int sdst0 = w * 1024;
  f32x4 acc[8][4] = {};
#pragma unroll
  for (int u = 0; u < 3; ++u) {
    char* d = lds + u * 32768;
    gload16(sA0 + u * 32, (bf16_t*)(d + sdst0));
    gload16(sA1 + u * 32, (bf16_t*)(d + 8192 + sdst0));
    gload16(sB0 + u * 32, (bf16_t*)(d + 16384 + sdst0));
    gload16(sB1 + u * 32, (bf16_t*)(d + 24576 + sdst0));
  }
  asm volatile("s_waitcnt vmcnt(8)" ::: "memory");
  __builtin_amdgcn_s_barrier();
  int t = 0;
  for (; t < NT - 3; ++t) TILE(t, "8", true);
  TILE(t, "4", false); ++t;
  TILE(t, "0", false); ++t;
  TILE(t, "0", false);
#pragma unroll
  for (int i = 0; i < 8; ++i)
#pragma unroll
    for (int j = 0; j < 4; ++j)
#pragma unroll
      for (int r = 0; r < 4; ++r) {
        long row = bm + wm * 128 + i * 16 + g * 4 + r;
        long col = bn + wn * 64 + j * 16 + r16;
        if (OUT_BF16) ((bf16_t*)Cout)[row * N + col] = (bf16_t)acc[i][j][r];
        else          ((float*)Cout)[row * N + col]  = acc[i][j][r];
      }
}

// ---------------- RoPE (neox), in-place on q,k of qkv ----------------
__global__ __launch_bounds__(256) void rope_kernel(bf16_t* __restrict__ qkv) {
  long idx = (long)blockIdx.x * 256 + threadIdx.x;
  int i = (int)(idx & 127);
  long rem = idx >> 7;
  int head = (int)(rem % 24);
  int s = (int)(rem / 24);
  int base = head < NQH ? head * DH : Q_SIZE + (head - NQH) * DH;
  long p1 = (long)s * QKV_COLS + base + i;
  long p2 = p1 + 128;
  float x1 = (float)qkv[p1], x2 = (float)qkv[p2];
  float inv_freq = exp2f((float)i * -0.10381025296522976f);
  float fr = (float)s * inv_freq;
  float sn, cs;
  sincosf(fr, &sn, &cs);
  qkv[p1] = (bf16_t)(x1 * cs - x2 * sn);
  qkv[p2] = (bf16_t)(x2 * cs + x1 * sn);
}

// ---------------- V transpose: vt[kv_col][s] = qkv[s][6144 + kv_col] ----------------
__global__ __launch_bounds__(256) void vtrans_kernel(const bf16_t* __restrict__ qkv,
                                                     bf16_t* __restrict__ vt) {
  __shared__ bf16_t tile[64][72];
  int t = threadIdx.x;
  long s0 = (long)blockIdx.x * 64;
  long c0 = (long)blockIdx.y * 64;
#pragma unroll
  for (int it = 0; it < 2; ++it) {
    int u = t + it * 256;
    int sr = u >> 3, ch = u & 7;
    bf16x8 v = *(const bf16x8*)&qkv[(s0 + sr) * QKV_COLS + (Q_SIZE + KV_SIZE) + c0 + ch * 8];
    *(bf16x8*)&tile[sr][ch * 8] = v;
  }
  __syncthreads();
#pragma unroll
  for (int it = 0; it < 2; ++it) {
    int u = t + it * 256;
    int cr = u >> 3, ch = u & 7;
    bf16x8 o;
#pragma unroll
    for (int j = 0; j < 8; ++j) o[j] = tile[ch * 8 + j][cr];
    *(bf16x8*)&vt[(c0 + cr) * SEQ + s0 + ch * 8] = o;
  }
}

// ---------------- flash attention: softcap + sliding window + GQA ----------------
// Block: 128 q rows x 1 head, 8 waves x 16 rows. 64-key tiles, DOUBLE-BUFFERED
// K/V staging (issue t+1 before computing t -> barrier drain is cheap).
// Softmax folded: p = exp(38 - 100/(e+1)), e = exp(s*0.0025); fixed max 12.
// P path: round-6 proven layout (swizzled b16 scatter writes + b128 reads).
__global__ __launch_bounds__(512, 2) void attn_kernel(const bf16_t* __restrict__ qkv,
                                                      const bf16_t* __restrict__ vt,
                                                      bf16_t* __restrict__ attn_out) {
  __shared__ bf16_t Kb[2][64 * 256];   // 2 x 32 KB
  __shared__ bf16_t Vb[2][256 * 64];   // 2 x 32 KB
  __shared__ bf16_t Pl[8 * 1024];      // 16 KB, 2KB per wave, XOR-swizzled
  int tid = threadIdx.x;
  int lane = tid & 63, w = tid >> 6;
  int r16 = lane & 15, g = lane >> 4;
  int bid = blockIdx.x;
  int swz = (bid & 7) * 64 + (bid >> 3);
  int h = swz >> 5;
  int qb = swz & 31;
  int kvh = h >> 1;
  int qw = qb * 128 + w * 16;
  bf16x8 qf[8];
  long qoff = (long)(qw + r16) * QKV_COLS + h * DH + g * 8;
#pragma unroll
  for (int kk = 0; kk < 8; ++kk) qf[kk] = *(const bf16x8*)&qkv[qoff + kk * 32];
  f32x4 acc[16] = {};
  float lsum[4] = {};
  const bf16_t* kg = qkv + Q_SIZE + (long)kvh * DH;
  const bf16_t* vg = vt + (long)kvh * DH * SEQ;
  bf16_t* pw = Pl + w * 1024;
  int lo = qb * 128 - (WINDOW - 1);
  int t0 = lo > 0 ? (lo >> 6) : 0;
  int t1 = qb * 2 + 2;
  int qlo = qw, qhi = qw + 15;

#define ATTN_STAGE(TT)                                                                   \
  {                                                                                      \
    int b_ = (TT) & 1;                                                                   \
    int kb_ = (TT) * 64;                                                                 \
    _Pragma("unroll")                                                                    \
    for (int c = 0; c < 4; ++c) {                                                        \
      int rowk = w * 8 + c * 2 + (lane >> 5);                                            \
      gload16(kg + (long)(kb_ + rowk) * QKV_COLS + (((lane & 31) ^ (rowk & 7)) * 8),     \
              &Kb[b_][w * 2048 + c * 512]);                                              \
      int rowv = w * 32 + c * 8 + (lane >> 3);                                           \
      gload16(vg + (long)rowv * SEQ + kb_ + (((lane & 7) ^ (rowv & 7)) * 8),             \
              &Vb[b_][w * 2048 + c * 512]);                                              \
    }                                                                                    \
  }

  ATTN_STAGE(t0);
  __syncthreads();
  for (int tt = t0; tt < t1; ++tt) {
    if (tt + 1 < t1) ATTN_STAGE(tt + 1);
    int b = tt & 1;
    int kb = tt * 64;
    bool active = !(kb > qhi || kb + 63 < qlo - (WINDOW - 1));
    if (active) {
      bool full = (kb + 63 <= qlo) && (qhi - kb <= WINDOW - 1);
      // ---- QK^T: 32 MFMA ----
      f32x4 sc[4] = {};
      __builtin_amdgcn_s_setprio(1);
#pragma unroll
      for (int kk = 0; kk < 8; ++kk) {
        int sl = ((kk * 4 + g) ^ (r16 & 7)) * 8;
#pragma unroll
        for (int c = 0; c < 4; ++c) {
          bf16x8 kf = *(const bf16x8*)&Kb[b][(c * 16 + r16) * 256 + sl];
          sc[c] = __builtin_amdgcn_mfma_f32_16x16x32_bf16(qf[kk], kf, sc[c], 0, 0, 0);
        }
      }
      __builtin_amdgcn_s_setprio(0);
      // ---- folded softcap+softmax: p = exp(38 - 100/(e+1)), e = exp(s*0.0025) ----
#pragma unroll
      for (int c = 0; c < 4; ++c)
#pragma unroll
        for (int r = 0; r < 4; ++r) {
          float s = sc[c][r];
          float e = __expf(s * (2.0f * SCALE_F / CAP_F));
          float rr = __builtin_amdgcn_rcpf(e + 1.0f);
          float p = __expf(fmaf(-100.0f, rr, 38.0f));
          if (!full) {
            int q = qw + g * 4 + r;
            int k = kb + c * 16 + r16;
            p = ((k <= q) && (q - k < WINDOW)) ? p : 0.0f;
          }
          lsum[r] += p;
          int prow = g * 4 + r;
          int pbyte = prow * 128 + ((c * 32 + r16 * 2) ^ ((prow & 7) << 4));
          *(bf16_t*)((char*)pw + pbyte) = (bf16_t)p;
        }
      // ---- P fragments (b128 reads, round-6 layout) ----
      bf16x8 pa[2];
#pragma unroll
      for (int pk = 0; pk < 2; ++pk) {
        int pb = r16 * 128 + ((pk * 64 + g * 16) ^ ((r16 & 7) << 4));
        pa[pk] = *(const bf16x8*)((const char*)pw + pb);
      }
      // ---- PV: 32 MFMA ----
      __builtin_amdgcn_s_setprio(1);
#pragma unroll
      for (int dt = 0; dt < 16; ++dt) {
        int vrow = (dt * 16 + r16) * 64;
        bf16x8 vf0 = *(const bf16x8*)&Vb[b][vrow + ((g ^ (r16 & 7)) * 8)];
        acc[dt] = __builtin_amdgcn_mfma_f32_16x16x32_bf16(pa[0], vf0, acc[dt], 0, 0, 0);
        bf16x8 vf1 = *(const bf16x8*)&Vb[b][vrow + (((4 + g) ^ (r16 & 7)) * 8)];
        acc[dt] = __builtin_amdgcn_mfma_f32_16x16x32_bf16(pa[1], vf1, acc[dt], 0, 0, 0);
      }
      __builtin_amdgcn_s_setprio(0);
    }
    __syncthreads();
  }
  // ---- normalize + write ----
  float inv[4];
#pragma unroll
  for (int r = 0; r < 4; ++r) {
    float s = lsum[r];
    s += __shfl_xor(s, 1);
    s += __shfl_xor(s, 2);
    s += __shfl_xor(s, 4);
    s += __shfl_xor(s, 8);
    inv[r] = 1.0f / s;
  }
#pragma unroll
  for (int dt = 0; dt < 16; ++dt)
#pragma unroll
    for (int r = 0; r < 4; ++r) {
      long row = qw + g * 4 + r;
      attn_out[row * Q_SIZE + h * DH + dt * 16 + r16] = (bf16_t)(acc[dt][r] * inv[r]);
    }
}

extern "C" void kernel_launch(void* const* d_in, const int* in_sizes, int n_in,
                              void* d_out, int out_size, void* d_ws, size_t ws_size,
                              hipStream_t stream) {
  const float* hid_f  = (const float*)d_in[1];
  const float* wqkv_f = (const float*)d_in[2];
  const float* wo_f   = (const float*)d_in[3];
  float* out = (float*)d_out;
  char* ws = (char*)d_ws;
  bf16_t* qkv    = (bf16_t*)(ws);                 // 67,108,864
  bf16_t* wo_b   = (bf16_t*)(ws + 67108864);      // 29,360,128
  bf16_t* hid_b  = (bf16_t*)(ws + 96468992);      // 29,360,128
  bf16_t* wqkv_b = (bf16_t*)(ws + 125829120);     // 58,720,256
  bf16_t* attn_b = (bf16_t*)(ws + 96468992);      // alias over hid_b (dead after GEMM1)
  bf16_t* vt     = (bf16_t*)(ws + 130023424);     // alias over wqkv tail (dead after GEMM1)

  cvt_f32_to_bf16<<<7168, 256, 0, stream>>>(hid_f, hid_b, 14680064 / 8);
  cvt_f32_to_bf16<<<14336, 256, 0, stream>>>(wqkv_f, wqkv_b, 29360128 / 8);
  cvt_f32_to_bf16<<<7168, 256, 0, stream>>>(wo_f, wo_b, 14680064 / 8);
  gemm_bt<HIDDEN, true><<<512, 512, 0, stream>>>(hid_b, wqkv_b, qkv, QKV_COLS);
  rope_kernel<<<49152, 256, 0, stream>>>(qkv);
  vtrans_kernel<<<dim3(64, 32), 256, 0, stream>>>(qkv, vt);
  attn_kernel<<<512, 512, 0, stream>>>(qkv, vt, attn_b);
  gemm_bt<Q_SIZE, false><<<224, 512, 0, stream>>>(attn_b, wo_b, out, HIDDEN);
}